// Round 12
// baseline (213.589 us; speedup 1.0000x reference)
//
#include <hip/hip_runtime.h>
#include <hip/hip_bf16.h>

// GNN_65498251264428: 2-layer GraphConv + mean pool + Linear(64,1).
// N=100000 nodes, E=1000000 edges, F=H=64, G=128 graphs.
//
// Layer-2 algebraic collapse (layer 2 is linear):
//   out[g] = (u.T_g + v.S_g)/c_g + (w_lin.b2_rel + b_lin)
//   u = w2_rel^T w_lin, v = w2_root^T w_lin
//   S_g -> per-node scalar q_i = v.h1_i ; T_g -> per-edge w_e * p_{src}
//
// Round 21: R11=204us; budget: gather 43 (wall) + small kernels ~40 +
// harness ws-poison fill 44 (untouchable) + ~75us launch overhead
// (~12us/dispatch from R7-vs-R11 cross-check). Cut 5 -> 4 dispatches:
// bucket_fill made histogram-free via FIXED-capacity ebuf slots per
// (fill-block, bucket) -- pos = (fb*196+bkt)*96+rank, rank from LDS counter
// (Binomial(4096,1/196): mean 21, sigma 4.6 -> CAP 96 = 16sigma, clamped).
// Fill then depends on NOTHING from prep -> fused into prep as extra
// blocks. csr_build column-sums lhmat[245][196] for bases, scans its
// column for run offsets, walks runs via LDS binsearch; same degree-scan ->
// place into compact CSR. gather (byte-identical R9) and pool unchanged.
// Pipeline: prep_fill -> csr_build -> gather -> pool (4 dispatches).

#define N_NODES 100000
#define N_EDGES 1000000
#define NGRAPHS 128
#define BN 512                              // nodes per bucket
#define NBUCK ((N_NODES + BN - 1) / BN)     // 196
#define FILL_T 16                           // edges per thread in fill
#define FILL_TILE (256 * FILL_T)            // 4096
#define FILL_NB ((N_EDGES + FILL_TILE - 1) / FILL_TILE)  // 245
#define CAPB 96                             // slots per (fill-block, bucket)
#define NTILES (N_NODES / 16)               // 6250 (exact)
#define AST 72                              // LDS row stride in shorts

#define PREP_CVT_NB 3125                    // 800000/256 exact
#define FILL0 (PREP_CVT_NB + 1)             // 3126
#define PREP_TOTAL (FILL0 + FILL_NB)        // 3371

typedef __attribute__((ext_vector_type(8))) short bf16x8;
typedef __attribute__((ext_vector_type(8))) unsigned short u16x8;
typedef __attribute__((ext_vector_type(4))) float f32x4;
typedef __attribute__((ext_vector_type(2))) float f32x2;

__device__ __forceinline__ unsigned short f2bf(float f) {
    unsigned u = __float_as_uint(f);
    unsigned r = (u + 0x7FFFu + ((u >> 16) & 1u)) >> 16;  // RNE
    return (unsigned short)r;
}
__device__ __forceinline__ float bf2f(unsigned short h) {
    return __uint_as_float(((unsigned)h) << 16);
}
// 4 fp8 (one dword) -> f32 via HW cvt, FMA into a[0..3]
__device__ __forceinline__ void fma4(int w, float wt, float* a) {
    f32x2 lo = __builtin_amdgcn_cvt_pk_f32_fp8(w, false);
    f32x2 hi = __builtin_amdgcn_cvt_pk_f32_fp8(w, true);
    a[0] += wt * lo[0];
    a[1] += wt * lo[1];
    a[2] += wt * hi[0];
    a[3] += wt * hi[1];
}
__device__ __forceinline__ int pack4(float f0, float f1, float f2, float f3) {
    int w = __builtin_amdgcn_cvt_pk_fp8_f32(f0, f1, 0, false);
    w = __builtin_amdgcn_cvt_pk_fp8_f32(f2, f3, w, true);
    return w;
}
// 8 fp8 (int2) -> bf16x8 fragment (root-term decode)
__device__ __forceinline__ bf16x8 fp8_to_bf16x8(int2 rx) {
    f32x2 a0 = __builtin_amdgcn_cvt_pk_f32_fp8(rx.x, false);
    f32x2 a1 = __builtin_amdgcn_cvt_pk_f32_fp8(rx.x, true);
    f32x2 a2 = __builtin_amdgcn_cvt_pk_f32_fp8(rx.y, false);
    f32x2 a3 = __builtin_amdgcn_cvt_pk_f32_fp8(rx.y, true);
    bf16x8 o;
    o[0] = (short)f2bf(a0[0]); o[1] = (short)f2bf(a0[1]);
    o[2] = (short)f2bf(a1[0]); o[3] = (short)f2bf(a1[1]);
    o[4] = (short)f2bf(a2[0]); o[5] = (short)f2bf(a2[1]);
    o[6] = (short)f2bf(a3[0]); o[7] = (short)f2bf(a3[1]);
    return o;
}

// ---- kernel 0: cvt + weights/u/v/C/gc + histogram-free bucket fill ---------
// blocks [0,3125): x->fp8 cvt. block 3125: weights + u/v/C + gc-binsearch.
// blocks [3126,3371): fill -- rank in LDS, write to fixed (fb,bucket) slot,
// store run lengths in lhmat (unconditional; no zeroing of anything global).
__global__ __launch_bounds__(256) void prep_fill_kernel(
    const float* __restrict__ x, int* __restrict__ xf8,
    const float* __restrict__ w1rel, const float* __restrict__ w1root,
    const float* __restrict__ w2rel, const float* __restrict__ w2root,
    const float* __restrict__ wlin, const float* __restrict__ b2rel,
    const float* __restrict__ blin, unsigned short* __restrict__ whirel,
    unsigned short* __restrict__ wlorel, unsigned short* __restrict__ whiroot,
    unsigned short* __restrict__ wloroot, float* __restrict__ u,
    float* __restrict__ v, float* __restrict__ C,
    const int* __restrict__ ei, const float* __restrict__ ew,
    int2* __restrict__ ebuf, int* __restrict__ lhmat,
    const int* __restrict__ batch, float* __restrict__ gc, int E) {
    int tid = threadIdx.x;
    if (blockIdx.x < PREP_CVT_NB) {  // cvt part: 8 floats/thread
        int i = blockIdx.x * 256 + tid;
        const float4* xp = (const float4*)x + (size_t)i * 2;
        float4 a = xp[0], b = xp[1];
        int2 o8;
        o8.x = pack4(a.x, a.y, a.z, a.w);
        o8.y = pack4(b.x, b.y, b.z, b.w);
        *((int2*)xf8 + i) = o8;
        return;
    }
    if (blockIdx.x == PREP_CVT_NB) {  // weight prep + misc
        for (int k = tid; k < 4096; k += 256) {
            float a = w1rel[k];
            unsigned short hi = f2bf(a);
            whirel[k] = hi;
            wlorel[k] = f2bf(a - bf2f(hi));
            float b = w1root[k];
            unsigned short hb = f2bf(b);
            whiroot[k] = hb;
            wloroot[k] = f2bf(b - bf2f(hb));
        }
        if (tid < 64) {
            float uu = 0.f, vv = 0.f;
            for (int h = 0; h < 64; ++h) {
                float wl = wlin[h];
                uu += wl * w2rel[h * 64 + tid];
                vv += wl * w2root[h * 64 + tid];
            }
            u[tid] = uu;
            v[tid] = vv;
        }
        if (tid == 0) {
            float c = blin[0];
            for (int h = 0; h < 64; ++h) c += wlin[h] * b2rel[h];
            *C = c;
        }
        if (tid < NGRAPHS) {  // gc[g] via binary search (batch sorted)
            int g = tid;
            int lo = 0, hi = N_NODES;
            while (lo < hi) {
                int m = (lo + hi) >> 1;
                if (batch[m] < g) lo = m + 1; else hi = m;
            }
            int lo2 = lo, hi2 = N_NODES;
            while (lo2 < hi2) {
                int m = (lo2 + hi2) >> 1;
                if (batch[m] < g + 1) lo2 = m + 1; else hi2 = m;
            }
            gc[g] = (float)(lo2 - lo);
        }
        return;
    }
    {  // fill part: fixed-capacity slots, no global atomics
        __shared__ int lh[NBUCK];
        int fb = blockIdx.x - FILL0;
        for (int i = tid; i < NBUCK; i += 256) lh[i] = 0;
        __syncthreads();
        int base = fb * FILL_TILE;
        int2 rec[FILL_T];
        int meta[FILL_T];
#pragma unroll
        for (int i = 0; i < FILL_T; ++i) {
            int e = base + i * 256 + tid;
            meta[i] = -1;
            if (e < E) {
                int src = ei[e];
                int dst = ei[E + e];
                int b = dst >> 9;
                int r = atomicAdd(&lh[b], 1);  // rank within (block,bucket)
                rec[i].x = src | ((dst & (BN - 1)) << 17);
                rec[i].y = __float_as_int(ew[e]);
                if (r < CAPB) meta[i] = (b << 13) | r;  // 16-sigma clamp
            }
        }
        __syncthreads();
        for (int i = tid; i < NBUCK; i += 256)
            lhmat[fb * NBUCK + i] = min(lh[i], CAPB);
        __syncthreads();
#pragma unroll
        for (int i = 0; i < FILL_T; ++i) {
            if (meta[i] >= 0) {
                int b = meta[i] >> 13;
                int r = meta[i] & 8191;
                ebuf[((size_t)fb * NBUCK + b) * CAPB + r] = rec[i];
            }
        }
    }
}

// map intra-bucket index i -> run kb via runoff (exclusive prefix, LDS)
__device__ __forceinline__ int find_run(const int* runoff, int i) {
    int lo = 0, hi = FILL_NB - 1;
    while (lo < hi) {
        int m = (lo + hi + 1) >> 1;
        if (runoff[m] <= i) lo = m; else hi = m - 1;
    }
    return lo;
}

// ---- kernel 1: csr_build from run-structured ebuf --------------------------
// One 512-thread block per bucket. Bucket bases from lhmat column sums +
// 196-scan; run offsets from this bucket's lhmat column + 245-scan; then
// degree-count -> scan -> place into COMPACT csr + row_ptr. Block 0 zeroes
// gp/gq/done (consumed only by the later pool kernel).
__global__ __launch_bounds__(512) void csr_build(
    const int* __restrict__ lhmat, const int2* __restrict__ ebuf,
    const int* __restrict__ batch, int* __restrict__ row_ptr,
    int2* __restrict__ csr, float* __restrict__ gp, float* __restrict__ gq,
    int* __restrict__ done, int N) {
    __shared__ int s[512];
    __shared__ int runoff[FILL_NB + 1];
    __shared__ int deg[BN];
    __shared__ int cur[BN];
    int t = threadIdx.x;
    int b = blockIdx.x;
    if (b == 0) {
        if (t < NGRAPHS) { gp[t] = 0.f; gq[t] = 0.f; }
        if (t == NGRAPHS) *done = 0;
    }
    // bucket totals -> 196-wide scan (first 256 threads)
    int tot = 0;
    if (t < NBUCK)
        for (int f = 0; f < FILL_NB; ++f) tot += lhmat[f * NBUCK + t];
    if (t < 256) s[t] = (t < NBUCK) ? tot : 0;
    __syncthreads();
    for (int off = 1; off < 256; off <<= 1) {
        int xv = (t < 256 && t >= off) ? s[t - off] : 0;
        __syncthreads();
        if (t < 256) s[t] += xv;
        __syncthreads();
    }
    int beg = (b == 0) ? 0 : s[b - 1];
    __syncthreads();
    // run offsets: scan this bucket's lhmat column (245 values, 512-scan)
    int cnt = (t < FILL_NB) ? lhmat[t * NBUCK + b] : 0;
    s[t] = cnt;
    __syncthreads();
    for (int off = 1; off < 512; off <<= 1) {
        int xv = (t >= off) ? s[t - off] : 0;
        __syncthreads();
        s[t] += xv;
        __syncthreads();
    }
    if (t == 0) runoff[0] = 0;
    if (t < FILL_NB) runoff[t + 1] = s[t];
    __syncthreads();
    int count = runoff[FILL_NB];
    // degree count
    if (t < BN) deg[t] = 0;
    __syncthreads();
    for (int i = t; i < count; i += 512) {
        int kb = find_run(runoff, i);
        int2 rc = ebuf[((size_t)kb * NBUCK + b) * CAPB + (i - runoff[kb])];
        atomicAdd(&deg[(rc.x >> 17) & (BN - 1)], 1);
    }
    __syncthreads();
    int d = deg[t];
    s[t] = d;
    __syncthreads();
    for (int off = 1; off < BN; off <<= 1) {
        int xv = (t >= off) ? s[t - off] : 0;
        __syncthreads();
        s[t] += xv;
        __syncthreads();
    }
    int excl = s[t] - d;
    int gidx = b * BN + t;
    if (gidx <= N) row_ptr[gidx] = beg + excl;  // covers row_ptr[N]=E too
    cur[t] = beg + excl;
    __syncthreads();
    // place
    for (int i = t; i < count; i += 512) {
        int kb = find_run(runoff, i);
        int2 rc = ebuf[((size_t)kb * NBUCK + b) * CAPB + (i - runoff[kb])];
        int dlo = (rc.x >> 17) & (BN - 1);
        int g = batch[b * BN + dlo];  // L1-hot (few lines per bucket)
        int r = atomicAdd(&cur[dlo], 1);
        int2 o;
        o.x = (rc.x & 0x1FFFF) | (g << 17);  // src | graph<<17
        o.y = rc.y;                          // weight bits
        csr[r] = o;
    }
}

// ---- kernel 2: fused gather + MFMA dense (byte-identical to R9/R11) --------
__global__ __launch_bounds__(256) void gather_dense_kernel(
    const unsigned char* __restrict__ xf8,
    const int* __restrict__ row_ptr, const int2* __restrict__ csr,
    const unsigned short* __restrict__ whirel,
    const unsigned short* __restrict__ wlorel,
    const unsigned short* __restrict__ whiroot,
    const unsigned short* __restrict__ wloroot,
    const float* __restrict__ b1rel, const float* __restrict__ u,
    const float* __restrict__ v, float* __restrict__ p, float* __restrict__ q,
    int ntiles) {
    __shared__ unsigned short arow[4][16 * AST];
    int lane = threadIdx.x & 63;
    int wv = threadIdx.x >> 6;
    int wave = (blockIdx.x << 2) + wv;
    if (wave >= ntiles) return;
    unsigned short* my = &arow[wv][0];
    int nb = wave * 16;

    // ---- phase 1: gather 16 node rows into LDS (fp8, 1 line/edge) ----
    {
        int g4 = lane >> 2;  // node 0..15
        int c4 = lane & 3;   // 16-feature chunk
        int node = nb + g4;
        int beg = row_ptr[node], end = row_ptr[node + 1];
        float a[16];
#pragma unroll
        for (int t = 0; t < 16; ++t) a[t] = 0.f;
        const unsigned char* xb = xf8 + (size_t)c4 * 16;
        for (int j = beg; j < end; j += 4) {
            int i1 = (j + 1 < end) ? j + 1 : j;
            int i2 = (j + 2 < end) ? j + 2 : j;
            int i3 = (j + 3 < end) ? j + 3 : j;
            int2 e0 = csr[j];
            int2 e1 = csr[i1];
            int2 e2 = csr[i2];
            int2 e3 = csr[i3];
            int4 r0 = *(const int4*)(xb + (size_t)(e0.x & 0x1FFFF) * 64);
            int4 r1 = *(const int4*)(xb + (size_t)(e1.x & 0x1FFFF) * 64);
            int4 r2 = *(const int4*)(xb + (size_t)(e2.x & 0x1FFFF) * 64);
            int4 r3 = *(const int4*)(xb + (size_t)(e3.x & 0x1FFFF) * 64);
            float w0 = __int_as_float(e0.y);
            float w1 = (j + 1 < end) ? __int_as_float(e1.y) : 0.f;
            float w2 = (j + 2 < end) ? __int_as_float(e2.y) : 0.f;
            float w3 = (j + 3 < end) ? __int_as_float(e3.y) : 0.f;
            fma4(r0.x, w0, a + 0);
            fma4(r0.y, w0, a + 4);
            fma4(r0.z, w0, a + 8);
            fma4(r0.w, w0, a + 12);
            fma4(r1.x, w1, a + 0);
            fma4(r1.y, w1, a + 4);
            fma4(r1.z, w1, a + 8);
            fma4(r1.w, w1, a + 12);
            fma4(r2.x, w2, a + 0);
            fma4(r2.y, w2, a + 4);
            fma4(r2.z, w2, a + 8);
            fma4(r2.w, w2, a + 12);
            fma4(r3.x, w3, a + 0);
            fma4(r3.y, w3, a + 4);
            fma4(r3.z, w3, a + 8);
            fma4(r3.w, w3, a + 12);
        }
        u16x8 o0, o1;
#pragma unroll
        for (int t = 0; t < 8; ++t) {
            o0[t] = f2bf(a[t]);
            o1[t] = f2bf(a[8 + t]);
        }
        *(u16x8*)(my + g4 * AST + c4 * 16) = o0;
        *(u16x8*)(my + g4 * AST + c4 * 16 + 8) = o1;
    }

    // ---- phase 2: MFMA dense on the 16-node tile ----
    int lo4 = lane & 15;
    int quad = lane >> 4;
    f32x4 acc4[4];
#pragma unroll
    for (int t = 0; t < 4; ++t) acc4[t] = (f32x4){0.f, 0.f, 0.f, 0.f};
#pragma unroll
    for (int s = 0; s < 2; ++s) {  // K-step: f in [s*32, s*32+32)
        bf16x8 Aa = *(const bf16x8*)(my + lo4 * AST + s * 32 + quad * 8);
        int2 rx = *(const int2*)(xf8 + (size_t)(nb + lo4) * 64 + s * 32 +
                                 quad * 8);
        bf16x8 Ax = fp8_to_bf16x8(rx);
#pragma unroll
        for (int t = 0; t < 4; ++t) {  // h-tile: h in [t*16, t*16+16)
            int off = (t * 16 + lo4) * 64 + s * 32 + quad * 8;
            bf16x8 bhr = *(const bf16x8*)(whirel + off);
            bf16x8 blr = *(const bf16x8*)(wlorel + off);
            bf16x8 bhx = *(const bf16x8*)(whiroot + off);
            bf16x8 blx = *(const bf16x8*)(wloroot + off);
            acc4[t] = __builtin_amdgcn_mfma_f32_16x16x32_bf16(Aa, bhr, acc4[t],
                                                              0, 0, 0);
            acc4[t] = __builtin_amdgcn_mfma_f32_16x16x32_bf16(Aa, blr, acc4[t],
                                                              0, 0, 0);
            acc4[t] = __builtin_amdgcn_mfma_f32_16x16x32_bf16(Ax, bhx, acc4[t],
                                                              0, 0, 0);
            acc4[t] = __builtin_amdgcn_mfma_f32_16x16x32_bf16(Ax, blx, acc4[t],
                                                              0, 0, 0);
        }
    }

    float pc[4] = {0.f, 0.f, 0.f, 0.f};
    float qc[4] = {0.f, 0.f, 0.f, 0.f};
#pragma unroll
    for (int t = 0; t < 4; ++t) {
        float bb = b1rel[t * 16 + lo4];
        float uu = u[t * 16 + lo4];
        float vv = v[t * 16 + lo4];
#pragma unroll
        for (int r = 0; r < 4; ++r) {
            float h1 = fmaxf(acc4[t][r] + bb, 0.f);
            pc[r] += uu * h1;
            qc[r] += vv * h1;
        }
    }
#pragma unroll
    for (int off = 1; off < 16; off <<= 1) {
#pragma unroll
        for (int r = 0; r < 4; ++r) {
            pc[r] += __shfl_xor(pc[r], off);
            qc[r] += __shfl_xor(qc[r], off);
        }
    }
    if (lo4 == 0) {  // lanes 0,16,32,48: nodes nb+quad*4 .. +3
        f32x4 po = {pc[0], pc[1], pc[2], pc[3]};
        f32x4 qo = {qc[0], qc[1], qc[2], qc[3]};
        *(f32x4*)(p + nb + quad * 4) = po;
        *(f32x4*)(q + nb + quad * 4) = qo;
    }
}

// ---- kernel 3: fused pooling + last-block epilogue -------------------------
#define PT_EPT 8
#define PT_EPW (64 * PT_EPT)   // 512 edges per wave
#define PT_NB ((N_EDGES + 4 * PT_EPW - 1) / (4 * PT_EPW))  // 489
#define PS_NB 98
__global__ __launch_bounds__(256) void pool_both(
    const int2* __restrict__ csr, const float* __restrict__ p,
    const float* __restrict__ q, const int* __restrict__ batch,
    float* __restrict__ gp, float* __restrict__ gq,
    const float* __restrict__ gc, int* __restrict__ done,
    const float* __restrict__ C, float* __restrict__ out, int E, int N) {
    __shared__ float lbuf[NGRAPHS];
    __shared__ int amLast;
    int tid = threadIdx.x;
    if (tid < NGRAPHS) lbuf[tid] = 0.f;
    __syncthreads();
    if (blockIdx.x < PT_NB) {
        int lane = tid & 63;
        int wid = (blockIdx.x * 256 + tid) >> 6;
        int base = wid * PT_EPW;
        float acc = 0.f;
        int curg = -1;
#pragma unroll
        for (int i = 0; i < PT_EPT; ++i) {
            int j = base + i * 64 + lane;
            if (j < E) {
                int2 e = csr[j];
                int g = ((unsigned)e.x) >> 17;
                float val = __int_as_float(e.y) * p[e.x & 0x1FFFF];
                if (g != curg) {
                    if (curg >= 0) atomicAdd(&lbuf[curg], acc);
                    curg = g;
                    acc = 0.f;
                }
                acc += val;
            }
        }
        if (curg >= 0) atomicAdd(&lbuf[curg], acc);
        __syncthreads();
        if (tid < NGRAPHS) {
            float t = lbuf[tid];
            if (t != 0.f) atomicAdd(&gp[tid], t);
        }
    } else {
        int bid = blockIdx.x - PT_NB;
        for (int i = bid * 256 + tid; i < N; i += PS_NB * 256) {
            atomicAdd(&lbuf[batch[i]], q[i]);
        }
        __syncthreads();
        if (tid < NGRAPHS) {
            float t = lbuf[tid];
            if (t != 0.f) atomicAdd(&gq[tid], t);
        }
    }
    __syncthreads();
    if (tid == 0) {
        __threadfence();
        amLast = (atomicAdd(done, 1) == PT_NB + PS_NB - 1);
    }
    __syncthreads();
    if (amLast) {
        __threadfence();
        if (tid < NGRAPHS) {
            float pv = atomicAdd(&gp[tid], 0.f);
            float qv = atomicAdd(&gq[tid], 0.f);
            float cv = atomicAdd((float*)&gc[tid], 0.f);
            out[tid] = (pv + qv) / fmaxf(cv, 1.f) + C[0];
        }
    }
}

extern "C" void kernel_launch(void* const* d_in, const int* in_sizes, int n_in,
                              void* d_out, int out_size, void* d_ws,
                              size_t ws_size, hipStream_t stream) {
    const float* x      = (const float*)d_in[0];
    const int*   ei     = (const int*)d_in[1];
    const float* ew     = (const float*)d_in[2];
    const int*   batch  = (const int*)d_in[3];
    const float* w1rel  = (const float*)d_in[4];
    const float* b1rel  = (const float*)d_in[5];
    const float* w1root = (const float*)d_in[6];
    const float* w2rel  = (const float*)d_in[7];
    const float* b2rel  = (const float*)d_in[8];
    const float* w2root = (const float*)d_in[9];
    const float* wlin   = (const float*)d_in[10];
    const float* blin   = (const float*)d_in[11];
    float* out = (float*)d_out;

    // ---- workspace layout ----
    // csr 8MB @0 | ebuf (run-slotted, 36.9MB) | xf8 6.4MB | weights |
    // p | q | u | v | C | gp gq gc done | lhmat | row_ptr.
    char* wsb = (char*)d_ws;
    int2* csr  = (int2*)wsb;                                   // 8 MB
    int2* ebuf = (int2*)(wsb + (size_t)N_EDGES * 8);
    char* tail = wsb + (size_t)N_EDGES * 8 +
                 (size_t)FILL_NB * NBUCK * CAPB * 8;
    int* xf8 = (int*)tail;                                     // N*64 bytes
    unsigned short* whirel  = (unsigned short*)(tail + (size_t)N_NODES * 64);
    unsigned short* wlorel  = whirel + 4096;
    unsigned short* whiroot = wlorel + 4096;
    unsigned short* wloroot = whiroot + 4096;
    float* p  = (float*)(wloroot + 4096);                      // N
    float* q  = p + N_NODES;                                   // N
    float* u  = q + N_NODES;                                   // 64
    float* v  = u + 64;                                        // 64
    float* C  = v + 64;                                        // 1
    float* gp = C + 1;                                         // 128
    float* gq = gp + NGRAPHS;                                  // 128
    float* gc = gq + NGRAPHS;                                  // 128
    int*   done   = (int*)(gc + NGRAPHS);                      // 1
    int*   lhmat  = done + 1;                                  // 245*196
    int*   row_ptr = lhmat + FILL_NB * NBUCK;                  // N+1

    prep_fill_kernel<<<PREP_TOTAL, 256, 0, stream>>>(
        x, xf8, w1rel, w1root, w2rel, w2root, wlin, b2rel, blin, whirel,
        wlorel, whiroot, wloroot, u, v, C, ei, ew, ebuf, lhmat, batch, gc,
        N_EDGES);

    csr_build<<<NBUCK, 512, 0, stream>>>(lhmat, ebuf, batch, row_ptr, csr,
                                         gp, gq, done, N_NODES);

    gather_dense_kernel<<<(NTILES + 3) / 4, 256, 0, stream>>>(
        (const unsigned char*)xf8, row_ptr, csr, whirel, wlorel, whiroot,
        wloroot, b1rel, u, v, p, q, NTILES);

    pool_both<<<PT_NB + PS_NB, 256, 0, stream>>>(csr, p, q, batch, gp, gq, gc,
                                                 done, C, out, N_EDGES,
                                                 N_NODES);
}

// Round 13
// 202.462 us; speedup vs baseline: 1.0550x; 1.0550x over previous
//
#include <hip/hip_runtime.h>
#include <hip/hip_bf16.h>

// GNN_65498251264428: 2-layer GraphConv + mean pool + Linear(64,1).
// N=100000 nodes, E=1000000 edges, F=H=64, G=128 graphs.
//
// Layer-2 algebraic collapse (layer 2 is linear):
//   out[g] = (u.T_g + v.S_g)/c_g + (w_lin.b2_rel + b_lin)
//   u = w2_rel^T w_lin, v = w2_root^T w_lin
//   S_g -> per-node scalar q_i = v.h1_i ; T_g -> per-edge w_e * p_{src}
//
// Round 22: REVERT to R11 (204.1us, best verified). R12's histogram-free
// fill + run-structured csr_build regressed (csr_build 12->49us: per-element
// LDS binary search x2 passes + run-strided ebuf reads). Both structural
// gambits (R10: fuse-into-gather killed occupancy; R12: run-walk serialized
// csr) confirm the R11 pipeline kernels are individually near-optimal and
// work-reshuffling loses more than a saved launch boundary gains.
// R11 = R9 gather (fp8 rows 1 line/edge, unroll-4 j-clamp, fp8-decoded
// root) + memset-free machinery (bpart partials, gc binsearch, cursor in
// prep, gp/gq/done in csr_build block 0).
// Pipeline: prep -> fill -> csr_build -> gather -> pool (5 dispatches,
// NO memset).

#define N_NODES 100000
#define N_EDGES 1000000
#define NGRAPHS 128
#define BN 512                              // nodes per bucket
#define NBUCK ((N_NODES + BN - 1) / BN)     // 196
#define FILL_T 16                           // edges per thread in bucket_fill
#define FILL_TILE (256 * FILL_T)            // 4096
#define FILL_NB ((N_EDGES + FILL_TILE - 1) / FILL_TILE)  // 245
#define NTILES (N_NODES / 16)               // 6250 (exact)
#define AST 72                              // LDS row stride in shorts

#define PREP_CVT_NB 3125                    // 800000/256 exact
#define HIST0 (PREP_CVT_NB + 1)             // 3126
#define HIST_NB 64
#define PREP_TOTAL (HIST0 + HIST_NB)        // 3190

typedef __attribute__((ext_vector_type(8))) short bf16x8;
typedef __attribute__((ext_vector_type(8))) unsigned short u16x8;
typedef __attribute__((ext_vector_type(4))) float f32x4;
typedef __attribute__((ext_vector_type(2))) float f32x2;

__device__ __forceinline__ unsigned short f2bf(float f) {
    unsigned u = __float_as_uint(f);
    unsigned r = (u + 0x7FFFu + ((u >> 16) & 1u)) >> 16;  // RNE
    return (unsigned short)r;
}
__device__ __forceinline__ float bf2f(unsigned short h) {
    return __uint_as_float(((unsigned)h) << 16);
}
// 4 fp8 (one dword) -> f32 via HW cvt, FMA into a[0..3]
__device__ __forceinline__ void fma4(int w, float wt, float* a) {
    f32x2 lo = __builtin_amdgcn_cvt_pk_f32_fp8(w, false);
    f32x2 hi = __builtin_amdgcn_cvt_pk_f32_fp8(w, true);
    a[0] += wt * lo[0];
    a[1] += wt * lo[1];
    a[2] += wt * hi[0];
    a[3] += wt * hi[1];
}
__device__ __forceinline__ int pack4(float f0, float f1, float f2, float f3) {
    int w = __builtin_amdgcn_cvt_pk_fp8_f32(f0, f1, 0, false);
    w = __builtin_amdgcn_cvt_pk_fp8_f32(f2, f3, w, true);
    return w;
}
// 8 fp8 (int2) -> bf16x8 fragment (root-term decode)
__device__ __forceinline__ bf16x8 fp8_to_bf16x8(int2 rx) {
    f32x2 a0 = __builtin_amdgcn_cvt_pk_f32_fp8(rx.x, false);
    f32x2 a1 = __builtin_amdgcn_cvt_pk_f32_fp8(rx.x, true);
    f32x2 a2 = __builtin_amdgcn_cvt_pk_f32_fp8(rx.y, false);
    f32x2 a3 = __builtin_amdgcn_cvt_pk_f32_fp8(rx.y, true);
    bf16x8 o;
    o[0] = (short)f2bf(a0[0]); o[1] = (short)f2bf(a0[1]);
    o[2] = (short)f2bf(a1[0]); o[3] = (short)f2bf(a1[1]);
    o[4] = (short)f2bf(a2[0]); o[5] = (short)f2bf(a2[1]);
    o[6] = (short)f2bf(a3[0]); o[7] = (short)f2bf(a3[1]);
    return o;
}

// ---- kernel 0: cvt + weights/u/v/C + gc-binsearch + cursor-zero + hist -----
__global__ __launch_bounds__(256) void prep_all_kernel(
    const float* __restrict__ x, int* __restrict__ xf8,
    const float* __restrict__ w1rel, const float* __restrict__ w1root,
    const float* __restrict__ w2rel, const float* __restrict__ w2root,
    const float* __restrict__ wlin, const float* __restrict__ b2rel,
    const float* __restrict__ blin, unsigned short* __restrict__ whirel,
    unsigned short* __restrict__ wlorel, unsigned short* __restrict__ whiroot,
    unsigned short* __restrict__ wloroot, float* __restrict__ u,
    float* __restrict__ v, float* __restrict__ C,
    const int* __restrict__ ei, int* __restrict__ bpart,
    const int* __restrict__ batch, float* __restrict__ gc,
    int* __restrict__ cursor, int E) {
    int tid = threadIdx.x;
    if (blockIdx.x < PREP_CVT_NB) {  // cvt part: 8 floats/thread
        int i = blockIdx.x * 256 + tid;
        const float4* xp = (const float4*)x + (size_t)i * 2;
        float4 a = xp[0], b = xp[1];
        int2 o8;
        o8.x = pack4(a.x, a.y, a.z, a.w);
        o8.y = pack4(b.x, b.y, b.z, b.w);
        *((int2*)xf8 + i) = o8;
        return;
    }
    if (blockIdx.x == PREP_CVT_NB) {  // weight prep + misc
        for (int k = tid; k < 4096; k += 256) {
            float a = w1rel[k];
            unsigned short hi = f2bf(a);
            whirel[k] = hi;
            wlorel[k] = f2bf(a - bf2f(hi));
            float b = w1root[k];
            unsigned short hb = f2bf(b);
            whiroot[k] = hb;
            wloroot[k] = f2bf(b - bf2f(hb));
        }
        if (tid < 64) {
            float uu = 0.f, vv = 0.f;
            for (int h = 0; h < 64; ++h) {
                float wl = wlin[h];
                uu += wl * w2rel[h * 64 + tid];
                vv += wl * w2root[h * 64 + tid];
            }
            u[tid] = uu;
            v[tid] = vv;
        }
        if (tid == 0) {
            float c = blin[0];
            for (int h = 0; h < 64; ++h) c += wlin[h] * b2rel[h];
            *C = c;
        }
        if (tid < NGRAPHS) {  // gc[g] via binary search (batch sorted)
            int g = tid;
            int lo = 0, hi = N_NODES;
            while (lo < hi) {
                int m = (lo + hi) >> 1;
                if (batch[m] < g) lo = m + 1; else hi = m;
            }
            int lo2 = lo, hi2 = N_NODES;
            while (lo2 < hi2) {
                int m = (lo2 + hi2) >> 1;
                if (batch[m] < g + 1) lo2 = m + 1; else hi2 = m;
            }
            gc[g] = (float)(lo2 - lo);
        }
        for (int i = tid; i < NBUCK; i += 256) cursor[i] = 0;
        return;
    }
    {  // dst-bucket histogram -> unconditional partial rows (no memset)
        __shared__ int lh[NBUCK];
        for (int i = tid; i < NBUCK; i += 256) lh[i] = 0;
        __syncthreads();
        int hb = blockIdx.x - HIST0;
        for (int e = hb * 256 + tid; e < E; e += HIST_NB * 256)
            atomicAdd(&lh[ei[E + e] >> 9], 1);
        __syncthreads();
        for (int i = tid; i < NBUCK; i += 256) bpart[hb * NBUCK + i] = lh[i];
    }
}

// ---- kernel 1: ranked bucket fill (bpart column-sum + local scan) ----------
__global__ __launch_bounds__(256) void bucket_fill(
    const int* __restrict__ ei, const float* __restrict__ ew,
    const int* __restrict__ bpart, int* __restrict__ cursor,
    int2* __restrict__ ebuf, int E) {
    __shared__ int lh[NBUCK];
    __shared__ int gbase[NBUCK];
    __shared__ int sc[256];
    __shared__ int lbo[NBUCK];
    int tid = threadIdx.x;
    for (int i = tid; i < NBUCK; i += 256) lh[i] = 0;
    int v = 0;
    if (tid < NBUCK)
        for (int h = 0; h < HIST_NB; ++h) v += bpart[h * NBUCK + tid];
    sc[tid] = (tid < NBUCK) ? v : 0;
    __syncthreads();
    for (int off = 1; off < 256; off <<= 1) {
        int x = (tid >= off) ? sc[tid - off] : 0;
        __syncthreads();
        sc[tid] += x;
        __syncthreads();
    }
    if (tid < NBUCK) lbo[tid] = sc[tid] - v;  // exclusive prefix
    __syncthreads();
    int base = blockIdx.x * FILL_TILE;
    int2 rec[FILL_T];
    int meta[FILL_T];
#pragma unroll
    for (int i = 0; i < FILL_T; ++i) {
        int e = base + i * 256 + tid;
        meta[i] = -1;
        if (e < E) {
            int src = ei[e];
            int dst = ei[E + e];
            int b = dst >> 9;
            int r = atomicAdd(&lh[b], 1);  // rank within (block,bucket)
            rec[i].x = src | ((dst & (BN - 1)) << 17);
            rec[i].y = __float_as_int(ew[e]);
            meta[i] = (b << 13) | r;  // r < 4096 fits 13 bits
        }
    }
    __syncthreads();
    for (int i = tid; i < NBUCK; i += 256) {
        int c = lh[i];
        gbase[i] = c ? (lbo[i] + atomicAdd(&cursor[i], c)) : 0;
    }
    __syncthreads();
#pragma unroll
    for (int i = 0; i < FILL_T; ++i) {
        if (meta[i] >= 0) {
            int b = meta[i] >> 13;
            int r = meta[i] & 8191;
            ebuf[gbase[b] + r] = rec[i];
        }
    }
}

// ---- kernel 2: per-bucket degree scan -> row_ptr; place CSR with graph id --
// Block 0 also zeroes gp/gq/done (used only by the later pool kernel).
__global__ __launch_bounds__(512) void csr_build(
    const int* __restrict__ bpart, const int2* __restrict__ ebuf,
    const int* __restrict__ batch, int* __restrict__ row_ptr,
    int2* __restrict__ csr, float* __restrict__ gp, float* __restrict__ gq,
    int* __restrict__ done, int N) {
    __shared__ int s[BN];
    int b = blockIdx.x;
    int t = threadIdx.x;
    if (b == 0) {
        if (t < NGRAPHS) { gp[t] = 0.f; gq[t] = 0.f; }
        if (t == NGRAPHS) *done = 0;
    }
    // bucket bases: column-sum bpart + 196-wide scan (first 256 threads)
    int vv = 0;
    if (t < NBUCK)
        for (int h = 0; h < HIST_NB; ++h) vv += bpart[h * NBUCK + t];
    if (t < 256) s[t] = (t < NBUCK) ? vv : 0;
    __syncthreads();
    for (int off = 1; off < 256; off <<= 1) {
        int x = (t >= off && t < 256) ? s[t - off] : 0;
        __syncthreads();
        if (t < 256) s[t] += x;
        __syncthreads();
    }
    int beg = (b == 0) ? 0 : s[b - 1];
    int end = s[b];
    __syncthreads();
    s[t] = 0;
    __syncthreads();
    for (int j = beg + t; j < end; j += 512)
        atomicAdd(&s[(ebuf[j].x >> 17) & (BN - 1)], 1);
    __syncthreads();
    int v = s[t];
    for (int off = 1; off < BN; off <<= 1) {
        int x = (t >= off) ? s[t - off] : 0;
        __syncthreads();
        s[t] += x;
        __syncthreads();
    }
    int excl = s[t] - v;
    int gidx = b * BN + t;
    if (gidx <= N) row_ptr[gidx] = beg + excl;  // covers row_ptr[N]=E too
    __syncthreads();
    s[t] = excl;  // becomes intra-bucket cursor
    __syncthreads();
    for (int j = beg + t; j < end; j += 512) {
        int2 rec = ebuf[j];
        int dlo = (rec.x >> 17) & (BN - 1);
        int g = batch[b * BN + dlo];  // L1-hot (1-2 lines per bucket)
        int r = atomicAdd(&s[dlo], 1);
        int2 o;
        o.x = (rec.x & 0x1FFFF) | (g << 17);  // src | graph<<17
        o.y = rec.y;                          // weight bits
        csr[beg + r] = o;
    }
}

// ---- kernel 3: fused gather + MFMA dense (byte-identical to R9) ------------
__global__ __launch_bounds__(256) void gather_dense_kernel(
    const unsigned char* __restrict__ xf8,
    const int* __restrict__ row_ptr, const int2* __restrict__ csr,
    const unsigned short* __restrict__ whirel,
    const unsigned short* __restrict__ wlorel,
    const unsigned short* __restrict__ whiroot,
    const unsigned short* __restrict__ wloroot,
    const float* __restrict__ b1rel, const float* __restrict__ u,
    const float* __restrict__ v, float* __restrict__ p, float* __restrict__ q,
    int ntiles) {
    __shared__ unsigned short arow[4][16 * AST];
    int lane = threadIdx.x & 63;
    int wv = threadIdx.x >> 6;
    int wave = (blockIdx.x << 2) + wv;
    if (wave >= ntiles) return;
    unsigned short* my = &arow[wv][0];
    int nb = wave * 16;

    // ---- phase 1: gather 16 node rows into LDS (fp8, 1 line/edge) ----
    {
        int g4 = lane >> 2;  // node 0..15
        int c4 = lane & 3;   // 16-feature chunk
        int node = nb + g4;
        int beg = row_ptr[node], end = row_ptr[node + 1];
        float a[16];
#pragma unroll
        for (int t = 0; t < 16; ++t) a[t] = 0.f;
        const unsigned char* xb = xf8 + (size_t)c4 * 16;
        for (int j = beg; j < end; j += 4) {
            int i1 = (j + 1 < end) ? j + 1 : j;
            int i2 = (j + 2 < end) ? j + 2 : j;
            int i3 = (j + 3 < end) ? j + 3 : j;
            int2 e0 = csr[j];
            int2 e1 = csr[i1];
            int2 e2 = csr[i2];
            int2 e3 = csr[i3];
            int4 r0 = *(const int4*)(xb + (size_t)(e0.x & 0x1FFFF) * 64);
            int4 r1 = *(const int4*)(xb + (size_t)(e1.x & 0x1FFFF) * 64);
            int4 r2 = *(const int4*)(xb + (size_t)(e2.x & 0x1FFFF) * 64);
            int4 r3 = *(const int4*)(xb + (size_t)(e3.x & 0x1FFFF) * 64);
            float w0 = __int_as_float(e0.y);
            float w1 = (j + 1 < end) ? __int_as_float(e1.y) : 0.f;
            float w2 = (j + 2 < end) ? __int_as_float(e2.y) : 0.f;
            float w3 = (j + 3 < end) ? __int_as_float(e3.y) : 0.f;
            fma4(r0.x, w0, a + 0);
            fma4(r0.y, w0, a + 4);
            fma4(r0.z, w0, a + 8);
            fma4(r0.w, w0, a + 12);
            fma4(r1.x, w1, a + 0);
            fma4(r1.y, w1, a + 4);
            fma4(r1.z, w1, a + 8);
            fma4(r1.w, w1, a + 12);
            fma4(r2.x, w2, a + 0);
            fma4(r2.y, w2, a + 4);
            fma4(r2.z, w2, a + 8);
            fma4(r2.w, w2, a + 12);
            fma4(r3.x, w3, a + 0);
            fma4(r3.y, w3, a + 4);
            fma4(r3.z, w3, a + 8);
            fma4(r3.w, w3, a + 12);
        }
        u16x8 o0, o1;
#pragma unroll
        for (int t = 0; t < 8; ++t) {
            o0[t] = f2bf(a[t]);
            o1[t] = f2bf(a[8 + t]);
        }
        *(u16x8*)(my + g4 * AST + c4 * 16) = o0;
        *(u16x8*)(my + g4 * AST + c4 * 16 + 8) = o1;
    }

    // ---- phase 2: MFMA dense on the 16-node tile ----
    int lo4 = lane & 15;
    int quad = lane >> 4;
    f32x4 acc4[4];
#pragma unroll
    for (int t = 0; t < 4; ++t) acc4[t] = (f32x4){0.f, 0.f, 0.f, 0.f};
#pragma unroll
    for (int s = 0; s < 2; ++s) {  // K-step: f in [s*32, s*32+32)
        bf16x8 Aa = *(const bf16x8*)(my + lo4 * AST + s * 32 + quad * 8);
        int2 rx = *(const int2*)(xf8 + (size_t)(nb + lo4) * 64 + s * 32 +
                                 quad * 8);
        bf16x8 Ax = fp8_to_bf16x8(rx);
#pragma unroll
        for (int t = 0; t < 4; ++t) {  // h-tile: h in [t*16, t*16+16)
            int off = (t * 16 + lo4) * 64 + s * 32 + quad * 8;
            bf16x8 bhr = *(const bf16x8*)(whirel + off);
            bf16x8 blr = *(const bf16x8*)(wlorel + off);
            bf16x8 bhx = *(const bf16x8*)(whiroot + off);
            bf16x8 blx = *(const bf16x8*)(wloroot + off);
            acc4[t] = __builtin_amdgcn_mfma_f32_16x16x32_bf16(Aa, bhr, acc4[t],
                                                              0, 0, 0);
            acc4[t] = __builtin_amdgcn_mfma_f32_16x16x32_bf16(Aa, blr, acc4[t],
                                                              0, 0, 0);
            acc4[t] = __builtin_amdgcn_mfma_f32_16x16x32_bf16(Ax, bhx, acc4[t],
                                                              0, 0, 0);
            acc4[t] = __builtin_amdgcn_mfma_f32_16x16x32_bf16(Ax, blx, acc4[t],
                                                              0, 0, 0);
        }
    }

    float pc[4] = {0.f, 0.f, 0.f, 0.f};
    float qc[4] = {0.f, 0.f, 0.f, 0.f};
#pragma unroll
    for (int t = 0; t < 4; ++t) {
        float bb = b1rel[t * 16 + lo4];
        float uu = u[t * 16 + lo4];
        float vv = v[t * 16 + lo4];
#pragma unroll
        for (int r = 0; r < 4; ++r) {
            float h1 = fmaxf(acc4[t][r] + bb, 0.f);
            pc[r] += uu * h1;
            qc[r] += vv * h1;
        }
    }
#pragma unroll
    for (int off = 1; off < 16; off <<= 1) {
#pragma unroll
        for (int r = 0; r < 4; ++r) {
            pc[r] += __shfl_xor(pc[r], off);
            qc[r] += __shfl_xor(qc[r], off);
        }
    }
    if (lo4 == 0) {  // lanes 0,16,32,48: nodes nb+quad*4 .. +3
        f32x4 po = {pc[0], pc[1], pc[2], pc[3]};
        f32x4 qo = {qc[0], qc[1], qc[2], qc[3]};
        *(f32x4*)(p + nb + quad * 4) = po;
        *(f32x4*)(q + nb + quad * 4) = qo;
    }
}

// ---- kernel 4: fused pooling + last-block epilogue -------------------------
#define PT_EPT 8
#define PT_EPW (64 * PT_EPT)   // 512 edges per wave
#define PT_NB ((N_EDGES + 4 * PT_EPW - 1) / (4 * PT_EPW))  // 489
#define PS_NB 98
__global__ __launch_bounds__(256) void pool_both(
    const int2* __restrict__ csr, const float* __restrict__ p,
    const float* __restrict__ q, const int* __restrict__ batch,
    float* __restrict__ gp, float* __restrict__ gq,
    const float* __restrict__ gc, int* __restrict__ done,
    const float* __restrict__ C, float* __restrict__ out, int E, int N) {
    __shared__ float lbuf[NGRAPHS];
    __shared__ int amLast;
    int tid = threadIdx.x;
    if (tid < NGRAPHS) lbuf[tid] = 0.f;
    __syncthreads();
    if (blockIdx.x < PT_NB) {
        int lane = tid & 63;
        int wid = (blockIdx.x * 256 + tid) >> 6;
        int base = wid * PT_EPW;
        float acc = 0.f;
        int curg = -1;
#pragma unroll
        for (int i = 0; i < PT_EPT; ++i) {
            int j = base + i * 64 + lane;
            if (j < E) {
                int2 e = csr[j];
                int g = ((unsigned)e.x) >> 17;
                float val = __int_as_float(e.y) * p[e.x & 0x1FFFF];
                if (g != curg) {
                    if (curg >= 0) atomicAdd(&lbuf[curg], acc);
                    curg = g;
                    acc = 0.f;
                }
                acc += val;
            }
        }
        if (curg >= 0) atomicAdd(&lbuf[curg], acc);
        __syncthreads();
        if (tid < NGRAPHS) {
            float t = lbuf[tid];
            if (t != 0.f) atomicAdd(&gp[tid], t);
        }
    } else {
        int bid = blockIdx.x - PT_NB;
        for (int i = bid * 256 + tid; i < N; i += PS_NB * 256) {
            atomicAdd(&lbuf[batch[i]], q[i]);
        }
        __syncthreads();
        if (tid < NGRAPHS) {
            float t = lbuf[tid];
            if (t != 0.f) atomicAdd(&gq[tid], t);
        }
    }
    __syncthreads();
    if (tid == 0) {
        __threadfence();
        amLast = (atomicAdd(done, 1) == PT_NB + PS_NB - 1);
    }
    __syncthreads();
    if (amLast) {
        __threadfence();
        if (tid < NGRAPHS) {
            float pv = atomicAdd(&gp[tid], 0.f);
            float qv = atomicAdd(&gq[tid], 0.f);
            float cv = atomicAdd((float*)&gc[tid], 0.f);
            out[tid] = (pv + qv) / fmaxf(cv, 1.f) + C[0];
        }
    }
}

extern "C" void kernel_launch(void* const* d_in, const int* in_sizes, int n_in,
                              void* d_out, int out_size, void* d_ws,
                              size_t ws_size, hipStream_t stream) {
    const float* x      = (const float*)d_in[0];
    const int*   ei     = (const int*)d_in[1];
    const float* ew     = (const float*)d_in[2];
    const int*   batch  = (const int*)d_in[3];
    const float* w1rel  = (const float*)d_in[4];
    const float* b1rel  = (const float*)d_in[5];
    const float* w1root = (const float*)d_in[6];
    const float* w2rel  = (const float*)d_in[7];
    const float* b2rel  = (const float*)d_in[8];
    const float* w2root = (const float*)d_in[9];
    const float* wlin   = (const float*)d_in[10];
    const float* blin   = (const float*)d_in[11];
    float* out = (float*)d_out;

    // ---- workspace layout ----
    // csr [0,8M) | ebuf [8M,16M) | xf8 (6.4M) | weights | p | q | u | v | C
    // | gp gq gc done | cursor | bpart | row_ptr.
    char* wsb = (char*)d_ws;
    int2* csr  = (int2*)wsb;                                   // 8 MB
    int2* ebuf = (int2*)(wsb + (size_t)N_EDGES * 8);           // 8 MB
    char* tail = wsb + (size_t)N_EDGES * 16;
    int* xf8 = (int*)tail;                                     // N*64 bytes
    unsigned short* whirel  = (unsigned short*)(tail + (size_t)N_NODES * 64);
    unsigned short* wlorel  = whirel + 4096;
    unsigned short* whiroot = wlorel + 4096;
    unsigned short* wloroot = whiroot + 4096;
    float* p  = (float*)(wloroot + 4096);                      // N
    float* q  = p + N_NODES;                                   // N
    float* u  = q + N_NODES;                                   // 64
    float* v  = u + 64;                                        // 64
    float* C  = v + 64;                                        // 1
    float* gp = C + 1;                                         // 128
    float* gq = gp + NGRAPHS;                                  // 128
    float* gc = gq + NGRAPHS;                                  // 128
    int*   done   = (int*)(gc + NGRAPHS);                      // 1
    int*   cursor = done + 1;                                  // NBUCK
    int*   bpart  = cursor + NBUCK;                            // 64*NBUCK
    int*   row_ptr = bpart + HIST_NB * NBUCK;                  // N+1

    prep_all_kernel<<<PREP_TOTAL, 256, 0, stream>>>(
        x, xf8, w1rel, w1root, w2rel, w2root, wlin, b2rel, blin, whirel,
        wlorel, whiroot, wloroot, u, v, C, ei, bpart, batch, gc, cursor,
        N_EDGES);

    bucket_fill<<<FILL_NB, 256, 0, stream>>>(ei, ew, bpart, cursor, ebuf,
                                             N_EDGES);

    csr_build<<<NBUCK, 512, 0, stream>>>(bpart, ebuf, batch, row_ptr, csr,
                                         gp, gq, done, N_NODES);

    gather_dense_kernel<<<(NTILES + 3) / 4, 256, 0, stream>>>(
        (const unsigned char*)xf8, row_ptr, csr, whirel, wlorel, whiroot,
        wloroot, b1rel, u, v, p, q, NTILES);

    pool_both<<<PT_NB + PS_NB, 256, 0, stream>>>(csr, p, q, batch, gp, gq, gc,
                                                 done, C, out, N_EDGES,
                                                 N_NODES);
}